// Round 4
// baseline (415.047 us; speedup 1.0000x reference)
//
#include <hip/hip_runtime.h>

namespace {
constexpr int D = 4096;   // d_model
constexpr int E = 64;     // n_experts
constexpr int M = 16384;  // B*S
constexpr int BM = 32;    // rows per block
constexpr int BK = 64;    // k per round
constexpr int NT = D / BK;    // 64 rounds
constexpr int NBLK = M / BM;  // 512 blocks -> 2 blocks/CU, 4 waves/SIMD

// output layout (floats, concatenated in reference return order)
constexpr int OFF_IDX = 0;         // [M][2]
constexpr int OFF_SCORES = 32768;  // [M][2]
constexpr int OFF_PROBS = 65536;   // [M][64]
constexpr int OFF_Z = 1114112;     // scalar
constexpr int OFF_IMP = 1114113;   // [64]
constexpr int OFF_LOAD = 1114177;  // [64]

constexpr int WS_STRIDE = 132;  // per-block stats: 64 imp | 64 cnt | 1 z2

constexpr int WOFF = 2048;   // Ws offset inside a staging buffer (Xs = 64k x 32r)
constexpr int BUFSZ = 6144;  // floats per staging buffer (24 KB)
}  // namespace

// ---------------------------------------------------------------------------
// Fused router. 512 blocks x 512 threads (2 blocks/CU). Per block: 32 rows,
// full K. 16 k-slices x 32 tiles (8 rows x 8 experts each). k-major LDS tiles
// with XOR-((k>>2)&7)<<2 swizzle: staging writes and b128 fragment reads are
// both conflict-free/2-way. Double-buffered, one barrier per round.
// ---------------------------------------------------------------------------
__global__ __launch_bounds__(512, 4) void router_fused(
    const float* __restrict__ xg, const float* __restrict__ wg,
    float* __restrict__ out, float* __restrict__ ws) {
  __shared__ float smem[16384];  // 64 KB; 2 blocks/CU = 128 KB <= 160 KB

  const int t = threadIdx.x;
  const int slice = t >> 5;  // 0..15 (4 k per round each)
  const int tile = t & 31;
  const int rg = tile >> 3;  // row group: 8 rows
  const int eg = tile & 7;   // expert group: 8 experts
  const int r0 = blockIdx.x * BM;

  // staging: thread loads 3 float4s (1 x-quad, 2 W-quads), coalesced
  const int srow = t >> 4;        // 0..31
  const int skq = (t & 15) * 4;   // k-quad base 0..60
  const int ssw = (t & 7) << 2;   // = ((skq>>2)&7)<<2, write swizzle
  const float* xp = xg + (size_t)(r0 + srow) * D + skq;
  const float* wp0 = wg + (size_t)srow * D + skq;
  const float* wp1 = wg + (size_t)(srow + 32) * D + skq;

  float4 vx, vw0, vw1;
  auto stage_load = [&](int k0) {
    vx = *(const float4*)(xp + k0);
    vw0 = *(const float4*)(wp0 + k0);
    vw1 = *(const float4*)(wp1 + k0);
  };
  auto stage_write = [&](float* buf) {
    float* Xs = buf;
    float* Ws = buf + WOFF;
    const int xr = srow ^ ssw;
    const int w0 = srow ^ ssw;
    const int w1 = (srow + 32) ^ ssw;  // ssw<32 so this is w0+32
    Xs[(skq + 0) * 32 + xr] = vx.x;
    Xs[(skq + 1) * 32 + xr] = vx.y;
    Xs[(skq + 2) * 32 + xr] = vx.z;
    Xs[(skq + 3) * 32 + xr] = vx.w;
    Ws[(skq + 0) * 64 + w0] = vw0.x;
    Ws[(skq + 1) * 64 + w0] = vw0.y;
    Ws[(skq + 2) * 64 + w0] = vw0.z;
    Ws[(skq + 3) * 64 + w0] = vw0.w;
    Ws[(skq + 0) * 64 + w1] = vw1.x;
    Ws[(skq + 1) * 64 + w1] = vw1.y;
    Ws[(skq + 2) * 64 + w1] = vw1.z;
    Ws[(skq + 3) * 64 + w1] = vw1.w;
  };

  // read swizzle is constant per slice: k = slice*4+kk -> (k>>2)&7 == slice&7
  const int sxr = (slice & 7) << 2;
  const int xb0 = (rg * 8) ^ sxr;      // rows rg*8..+3  (XOR keeps 16B align)
  const int xb1 = (rg * 8 + 4) ^ sxr;  // rows rg*8+4..+7
  const int wb0 = (eg * 8) ^ sxr;
  const int wb1 = (eg * 8 + 4) ^ sxr;

  float acc[8][8];
#pragma unroll
  for (int i = 0; i < 8; ++i)
#pragma unroll
    for (int j = 0; j < 8; ++j) acc[i][j] = 0.f;

  stage_load(0);
  stage_write(smem);

  for (int r = 0; r < NT; ++r) {
    __syncthreads();  // tile r staged; everyone done reading the other buffer
    if (r + 1 < NT) stage_load((r + 1) * BK);  // globals fly over compute

    const float* buf = smem + (r & 1) * BUFSZ;
    const float* Xs = buf + slice * 4 * 32;
    const float* Ws = buf + WOFF + slice * 4 * 64;
#pragma unroll
    for (int kk = 0; kk < 4; ++kk) {
      const float4 a0 = *(const float4*)&Xs[kk * 32 + xb0];
      const float4 a1 = *(const float4*)&Xs[kk * 32 + xb1];
      const float4 b0 = *(const float4*)&Ws[kk * 64 + wb0];
      const float4 b1 = *(const float4*)&Ws[kk * 64 + wb1];
      const float av[8] = {a0.x, a0.y, a0.z, a0.w, a1.x, a1.y, a1.z, a1.w};
      const float bv[8] = {b0.x, b0.y, b0.z, b0.w, b1.x, b1.y, b1.z, b1.w};
#pragma unroll
      for (int i = 0; i < 8; ++i)
#pragma unroll
        for (int j = 0; j < 8; ++j) acc[i][j] = fmaf(av[i], bv[j], acc[i][j]);
    }
    if (r + 1 < NT) stage_write(smem + ((r + 1) & 1) * BUFSZ);
  }
  __syncthreads();

  // ---- one-time 16-slice tree reduction through LDS (log2 phases) ----
  // slot layout: [slot][64] with a (tile*4)&63 quad rotation to spread banks.
#pragma unroll
  for (int half = 8; half >= 1; half >>= 1) {
    if (slice >= half && slice < 2 * half) {
      float* p = smem + (size_t)((slice - half) * 32 + tile) * 64;
#pragma unroll
      for (int i = 0; i < 8; ++i)
#pragma unroll
        for (int j4 = 0; j4 < 8; j4 += 4) {
          const int off = (i * 8 + j4 + tile * 4) & 63;
          float4 v = {acc[i][j4], acc[i][j4 + 1], acc[i][j4 + 2], acc[i][j4 + 3]};
          *(float4*)&p[off] = v;
        }
    }
    __syncthreads();
    if (slice < half) {
      const float* p = smem + (size_t)(slice * 32 + tile) * 64;
#pragma unroll
      for (int i = 0; i < 8; ++i)
#pragma unroll
        for (int j4 = 0; j4 < 8; j4 += 4) {
          const int off = (i * 8 + j4 + tile * 4) & 63;
          const float4 v = *(const float4*)&p[off];
          acc[i][j4] += v.x;
          acc[i][j4 + 1] += v.y;
          acc[i][j4 + 2] += v.z;
          acc[i][j4 + 3] += v.w;
        }
    }
    __syncthreads();
  }

  // ---- epilogue (smem repurposed; all staging/reduction reads done) ----
  float* Lg = smem;                    // [32][68], 16B-aligned rows
  float* rowmax = smem + 2176;         // [32]
  float* rowrs = rowmax + 32;          // [32]
  float* zrow = rowrs + 32;            // [32]
  int* cnt = (int*)(zrow + 32);        // [64]

  if (slice == 0) {  // slice 0 holds the fully reduced 32x64 logits
#pragma unroll
    for (int i = 0; i < 8; ++i)
#pragma unroll
      for (int j4 = 0; j4 < 8; j4 += 4) {
        float4 v = {acc[i][j4], acc[i][j4 + 1], acc[i][j4 + 2], acc[i][j4 + 3]};
        *(float4*)&Lg[(rg * 8 + i) * 68 + eg * 8 + j4] = v;
      }
  }
  if (t < 64) cnt[t] = 0;
  __syncthreads();

  // per-row scan: top-2 (lower index wins ties, matching lax.top_k) + lse
  if (t < 32) {
    const float* row = Lg + t * 68;
    float v1 = -3.402823466e+38f, v2 = -3.402823466e+38f;
    int i1 = 0, i2 = 0;
#pragma unroll 8
    for (int e = 0; e < 64; ++e) {
      const float x = row[e];
      if (x > v1) {
        v2 = v1; i2 = i1; v1 = x; i1 = e;
      } else if (x > v2) {
        v2 = x; i2 = e;
      }
    }
    float ssum = 0.f;
#pragma unroll 8
    for (int e = 0; e < 64; ++e) ssum += __expf(row[e] - v1);
    const float z = v1 + __logf(ssum);
    rowmax[t] = v1;
    rowrs[t] = 1.f / ssum;
    zrow[t] = z * z;

    const int r = r0 + t;
    out[OFF_IDX + 2 * r] = (float)i1;
    out[OFF_IDX + 2 * r + 1] = (float)i2;
    const float e1 = __expf(v2 - v1);  // v2 <= v1, stable
    const float s0 = 1.f / (1.f + e1);
    out[OFF_SCORES + 2 * r] = s0;
    out[OFF_SCORES + 2 * r + 1] = e1 * s0;
    atomicAdd(&cnt[i1], 1);
    atomicAdd(&cnt[i2], 1);
  }
  __syncthreads();

  // probs: 512 threads x 4 elements; write global + back to Lg for col sums
  {
    const int pr = t >> 4;
    const int pc = (t & 15) * 4;
    float* prow = Lg + pr * 68 + pc;
    const float m = rowmax[pr];
    const float rs = rowrs[pr];
    float4 v = *(const float4*)prow;
    v.x = __expf(v.x - m) * rs;
    v.y = __expf(v.y - m) * rs;
    v.z = __expf(v.z - m) * rs;
    v.w = __expf(v.w - m) * rs;
    *(float4*)&out[OFF_PROBS + (size_t)(r0 + pr) * 64 + pc] = v;
    *(float4*)prow = v;
  }
  __syncthreads();

  // per-block stats -> ws (no global atomics)
  if (t < 64) {
    float ic = 0.f;
#pragma unroll 8
    for (int rr = 0; rr < 32; ++rr) ic += Lg[rr * 68 + t];
    ws[(size_t)blockIdx.x * WS_STRIDE + t] = ic;
    ws[(size_t)blockIdx.x * WS_STRIDE + 64 + t] = (float)cnt[t];
  }
  if (t < 32) {
    float zz = zrow[t];
#pragma unroll
    for (int off = 16; off > 0; off >>= 1) zz += __shfl_xor(zz, off);
    if (t == 0) ws[(size_t)blockIdx.x * WS_STRIDE + 128] = zz;
  }
}

// ---------------------------------------------------------------------------
// Final reduction over 512 per-block stat slots.
// ---------------------------------------------------------------------------
__global__ __launch_bounds__(192) void router_reduce(
    const float* __restrict__ ws, float* __restrict__ out) {
  const int t = threadIdx.x;
  if (t < 129) {
    float v = 0.f;
#pragma unroll 8
    for (int b = 0; b < NBLK; ++b) v += ws[(size_t)b * WS_STRIDE + t];
    if (t < 64)
      out[OFF_IMP + t] = v * (1.f / 16384.f);
    else if (t < 128)
      // counts are integers; /32768 exact; denominator max(sum,1)=32768
      out[OFF_LOAD + (t - 64)] = v * (1.f / 32768.f);
    else
      out[OFF_Z] = v * (1.f / 16384.f);
  }
}

extern "C" void kernel_launch(void* const* d_in, const int* in_sizes, int n_in,
                              void* d_out, int out_size, void* d_ws, size_t ws_size,
                              hipStream_t stream) {
  const float* x = (const float*)d_in[0];
  const float* wgate = (const float*)d_in[1];
  float* out = (float*)d_out;
  float* ws = (float*)d_ws;  // 512*132 floats = 270 KB, fully rewritten each call

  router_fused<<<dim3(NBLK), dim3(512), 0, stream>>>(x, wgate, out, ws);
  router_reduce<<<dim3(1), dim3(192), 0, stream>>>(ws, out);
}